// Round 11
// baseline (175.894 us; speedup 1.0000x reference)
//
#include <hip/hip_runtime.h>
#include <stdint.h>

#define SEQ 2048
#define DMODEL 1024
#define NHEAD 16
#define HDIM 64
#define KCH 256    // keys per attn work item
#define NCH 8      // max chunks per q-block (SEQ/KCH)
// q-blocks of 32 rows: 64 per head. items per head = sum_{c=0..7}(64-8c) = 288.

typedef unsigned short u16;
typedef __attribute__((ext_vector_type(4))) float f32x4;
typedef __attribute__((ext_vector_type(8))) __bf16 bf16x8;
typedef __attribute__((ext_vector_type(8))) u16 u16x8;

__device__ __forceinline__ u16 f2bf(float f) {
  unsigned int u = __builtin_bit_cast(unsigned int, f);
  unsigned int r = (u + 0x7FFFu + ((u >> 16) & 1u)) >> 16;
  return (u16)r;
}
__device__ __forceinline__ float bf2f(u16 b) {
  unsigned int u = ((unsigned int)b) << 16;
  return __builtin_bit_cast(float, u);
}
__device__ __forceinline__ bf16x8 load8(const u16* p) {
  return __builtin_bit_cast(bf16x8, *(const u16x8*)p);
}
__device__ __forceinline__ void gl_lds16(const void* g, void* l) {
  __builtin_amdgcn_global_load_lds(
      (const __attribute__((address_space(1))) unsigned int*)g,
      (__attribute__((address_space(3))) unsigned int*)l, 16, 0, 0);
}
// DPP row_ror move (16-lane row domain). CTRL = 0x120 | n.
template <int CTRL>
__device__ __forceinline__ float dpp_mv(float x) {
  return __builtin_bit_cast(float,
      __builtin_amdgcn_update_dpp(0, __builtin_bit_cast(int, x), CTRL, 0xF, 0xF, false));
}
__device__ __forceinline__ float rowmax16(float v) {
  v = fmaxf(v, dpp_mv<0x121>(v));
  v = fmaxf(v, dpp_mv<0x122>(v));
  v = fmaxf(v, dpp_mv<0x124>(v));
  v = fmaxf(v, dpp_mv<0x128>(v));
  return v;
}
__device__ __forceinline__ float rowsum16(float v) {
  v += dpp_mv<0x121>(v);
  v += dpp_mv<0x122>(v);
  v += dpp_mv<0x124>(v);
  v += dpp_mv<0x128>(v);
  return v;
}

// ---------------- f32 -> bf16 convert (hidden_states) ----------------
__global__ __launch_bounds__(256) void convert_x(const float* __restrict__ X,
                                                 u16* __restrict__ Xb) {
  int i = (blockIdx.x * 256 + threadIdx.x) * 4;
  float4 v = *(const float4*)(X + i);
  union { u16 s[4]; uint2 u; } o;
  o.s[0] = f2bf(v.x); o.s[1] = f2bf(v.y); o.s[2] = f2bf(v.z); o.s[3] = f2bf(v.w);
  *(uint2*)(Xb + i) = o.u;
}

// ------------- weight transpose+convert: W[k][n] f32 -> Wt[n][k] bf16 -------------
__global__ __launch_bounds__(256) void transpose_w(
    const float* __restrict__ W0, const float* __restrict__ W1,
    const float* __restrict__ W2, const float* __restrict__ W3,
    u16* __restrict__ T0, u16* __restrict__ T1,
    u16* __restrict__ T2, u16* __restrict__ T3) {
  __shared__ u16 tile[64][65];
  int bz = blockIdx.z;
  const float* W = bz == 0 ? W0 : bz == 1 ? W1 : bz == 2 ? W2 : W3;
  u16* T = bz == 0 ? T0 : bz == 1 ? T1 : bz == 2 ? T2 : T3;
  int n0 = blockIdx.x * 64, k0 = blockIdx.y * 64;
  int t = threadIdx.x;
#pragma unroll 4
  for (int i = 0; i < 16; ++i) {
    int idx = i * 256 + t;
    int r = idx >> 6, c = idx & 63;
    tile[r][c] = f2bf(W[(k0 + r) * 1024 + n0 + c]);
  }
  __syncthreads();
#pragma unroll 4
  for (int i = 0; i < 16; ++i) {
    int idx = i * 256 + t;
    int r = idx >> 6, c = idx & 63;  // r = n-local, c = k-local
    T[(n0 + r) * 1024 + k0 + c] = tile[c][r];
  }
}

// ---------------- bf16 MFMA GEMM: C[M][n] = A[M][K] * W[K][n], B given as Wt[n][k] ----------------
template <int BM, int BN, int NMATS, bool OUTF32>
__global__ __launch_bounds__(256) void gemm_bf16(
    const u16* __restrict__ A, const u16* __restrict__ B0,
    const u16* __restrict__ B1, const u16* __restrict__ B2,
    u16* __restrict__ O0, u16* __restrict__ O1, u16* __restrict__ O2,
    float* __restrict__ OF) {
  constexpr int MI = BM / 32, NI = BN / 32;
  constexpr int LA = BM / 64, LB = BN / 64;
  __shared__ u16 As[BM * 32];
  __shared__ u16 Bs[BN * 32];
  const int t = threadIdx.x;
  const int lane = t & 63, w = t >> 6;
  const int g = lane >> 4, li = lane & 15;
  const int n0g = blockIdx.x * BN;
  const int mat = n0g >> 10;
  const int n0 = n0g & 1023;
  const u16* Bp = (NMATS == 1 || mat == 0) ? B0 : (mat == 1 ? B1 : B2);
  const int m0 = blockIdx.y * BM;
  const int wm = (w >> 1) * (BM / 2), wn = (w & 1) * (BN / 2);
  f32x4 acc[MI][NI] = {};
  for (int k0 = 0; k0 < 1024; k0 += 32) {
#pragma unroll
    for (int it = 0; it < LA; ++it) {
      int L = it * 2048 + t * 8;
      int r = L >> 5, c = L & 31;
      gl_lds16(A + (m0 + r) * 1024 + k0 + c, (char*)As + it * 4096 + w * 1024);
    }
#pragma unroll
    for (int it = 0; it < LB; ++it) {
      int L = it * 2048 + t * 8;
      int r = L >> 5, c = L & 31;
      gl_lds16(Bp + (n0 + r) * 1024 + k0 + c, (char*)Bs + it * 4096 + w * 1024);
    }
    __syncthreads();
    bf16x8 af[MI], bfr[NI];
#pragma unroll
    for (int mi = 0; mi < MI; ++mi) af[mi] = load8(&As[(wm + mi * 16 + li) * 32 + g * 8]);
#pragma unroll
    for (int ni = 0; ni < NI; ++ni) bfr[ni] = load8(&Bs[(wn + ni * 16 + li) * 32 + g * 8]);
#pragma unroll
    for (int mi = 0; mi < MI; ++mi)
#pragma unroll
      for (int ni = 0; ni < NI; ++ni)
        acc[mi][ni] = __builtin_amdgcn_mfma_f32_16x16x32_bf16(af[mi], bfr[ni], acc[mi][ni], 0, 0, 0);
    __syncthreads();
  }
  u16* Ob = (NMATS == 1 || mat == 0) ? O0 : (mat == 1 ? O1 : O2);
#pragma unroll
  for (int mi = 0; mi < MI; ++mi)
#pragma unroll
    for (int ni = 0; ni < NI; ++ni)
#pragma unroll
      for (int r = 0; r < 4; ++r) {
        // verified C/D layout: row = (lane>>4)*4 + r, col = lane&15
        int m = m0 + wm + mi * 16 + g * 4 + r;
        int n = n0 + wn + ni * 16 + li;
        float v = acc[mi][ni][r];
        if (OUTF32) OF[m * 1024 + n] = v;
        else Ob[m * 1024 + n] = f2bf(v);
      }
}

// ------- RoPE in-place on bf16 Q,K; fold 1/sqrt(HD) AND log2(e) into Q (exp2-domain softmax) -------
__global__ __launch_bounds__(256) void rope_qk(u16* __restrict__ Qb, u16* __restrict__ Kb,
                                               const int* __restrict__ pos_ids) {
  int gid = blockIdx.x * 256 + threadIdx.x;  // one per (s,h,pair)
  int s = gid >> 9;
  int rem = gid & 511;
  int h = rem >> 5, i = rem & 31;
  float pos = (float)pos_ids[s];
  float inv = exp2f(-(float)i * (13.287712379549449f / 32.0f));
  float ang = pos * inv;
  float sn, cs;
  sincosf(ang, &sn, &cs);
  int base = s * 1024 + h * 64 + 2 * i;
  const float qs = 0.125f * 1.4426950408889634f;  // 1/sqrt(64) * log2(e)
  {
    float x0 = bf2f(Qb[base]), x1 = bf2f(Qb[base + 1]);
    Qb[base]     = f2bf((x0 * cs - x1 * sn) * qs);
    Qb[base + 1] = f2bf((x0 * sn + x1 * cs) * qs);
  }
  {
    float x0 = bf2f(Kb[base]), x1 = bf2f(Kb[base + 1]);
    Kb[base]     = f2bf(x0 * cs - x1 * sn);
    Kb[base + 1] = f2bf(x0 * sn + x1 * cs);
  }
}

// ---------------- V transpose: Vb[s][h*64+d] -> Vt[h][d][s] ----------------
__global__ __launch_bounds__(256) void v_transpose(const u16* __restrict__ Vb,
                                                   u16* __restrict__ Vt) {
  __shared__ u16 tile[64][65];
  const int t = threadIdx.x;
  const int s0 = blockIdx.x * 64, h = blockIdx.y;
#pragma unroll 4
  for (int i = 0; i < 16; ++i) {
    int idx = i * 256 + t;
    int r = idx >> 6, c = idx & 63;
    tile[r][c] = Vb[(s0 + r) * 1024 + h * 64 + c];
  }
  __syncthreads();
#pragma unroll 4
  for (int i = 0; i < 16; ++i) {
    int idx = i * 256 + t;
    int d = idx >> 6, sc = idx & 63;
    Vt[h * (64 * 2048) + d * 2048 + s0 + sc] = tile[sc][d];
  }
}

// ---------------- split-K flash attention partial: QBLK=32, KVBLK=64, KCH=256 ----------------
// 1152 blocks x 4 waves = 288 waves/head = exactly 1 item per wave, max 4 iterations.
// __launch_bounds__(256,5): VGPR cap 102 (uses ~84), 5 blocks/CU -> capacity 1280 >= 1152,
// so ALL blocks co-resident -> latency hidden by TLP, no straggler round.
// head = bid & 15 -> one XCD per head (1152 % 16 == 0), K/V stay L2-hot.
// DPP row_ror 16-lane reduce (no LDS traffic); exp2-domain scores (Q pre-scaled by log2 e).
__global__ __launch_bounds__(256, 5) void attn_partial(
    const u16* __restrict__ Qb, const u16* __restrict__ Kb,
    const u16* __restrict__ Vt, const int* __restrict__ amask,
    float* __restrict__ Mpart, float* __restrict__ Lpart, u16* __restrict__ Opart) {
  const int t = threadIdx.x, lane = t & 63, w = t >> 6;
  const int g = lane >> 4, li = lane & 15;
  const int bid = blockIdx.x;
  const int h = bid & 15;
  const int j = (bid >> 4) * 4 + w;  // 0..287
  __shared__ u16 Plds[4][2][16][72];  // per-wave P tile [a][q16][64+8pad]
  const u16* Vh = Vt + h * (64 * 2048);
  // decode chunk c, q-block qb (32 rows); segment starts S_c = 64c - 4c(c-1)
  // = {0, 64, 120, 168, 208, 240, 264, 280}
  const int c = (j >= 280) ? 7 : (j >= 264) ? 6 : (j >= 240) ? 5 : (j >= 208) ? 4
              : (j >= 168) ? 3 : (j >= 120) ? 2 : (j >= 64) ? 1 : 0;
  const int qb = 8 * c + (j - (64 * c - 4 * c * (c - 1)));
  const int q0 = qb * 32;
  const int kstart = c * KCH;
  const int kend = min(kstart + KCH, q0 + 32);
  bf16x8 qf[2][2];
#pragma unroll
  for (int a = 0; a < 2; ++a)
#pragma unroll
    for (int hf = 0; hf < 2; ++hf)
      qf[a][hf] = load8(Qb + (q0 + a * 16 + li) * 1024 + h * 64 + hf * 32 + g * 8);
  f32x4 acc[2][4] = {};
  float mrow[2][4], lrow[2][4];
#pragma unroll
  for (int a = 0; a < 2; ++a)
#pragma unroll
    for (int r = 0; r < 4; ++r) { mrow[a][r] = -1e30f; lrow[a][r] = 0.f; }
  for (int k0 = kstart; k0 < kend; k0 += 64) {
    // padding mask for this 64-key tile: 1 load + ballot (k0+lane <= 2047 always)
    unsigned long long kmsk = __ballot(amask[k0 + lane] != 0);
    f32x4 sc[2][4] = {};
#pragma unroll
    for (int s = 0; s < 4; ++s) {
      bf16x8 kf0 = load8(Kb + (k0 + s * 16 + li) * 1024 + h * 64 + 0 + g * 8);
      bf16x8 kf1 = load8(Kb + (k0 + s * 16 + li) * 1024 + h * 64 + 32 + g * 8);
#pragma unroll
      for (int a = 0; a < 2; ++a) {
        sc[a][s] = __builtin_amdgcn_mfma_f32_16x16x32_bf16(qf[a][0], kf0, sc[a][s], 0, 0, 0);
        sc[a][s] = __builtin_amdgcn_mfma_f32_16x16x32_bf16(qf[a][1], kf1, sc[a][s], 0, 0, 0);
      }
    }
    // mask in place + in-lane fold over the 4 key-subtiles.
    // Score layout: q = a*16 + g*4 + r, key = s*16 + li.
    float tmax[2][4];
#pragma unroll
    for (int a = 0; a < 2; ++a)
#pragma unroll
      for (int r = 0; r < 4; ++r) tmax[a][r] = -1e30f;
    if (k0 + 63 <= q0) {  // full tile: causal always satisfied (wave-uniform branch)
#pragma unroll
      for (int s = 0; s < 4; ++s) {
        bool kok = ((kmsk >> (s * 16 + li)) & 1ull) != 0;
#pragma unroll
        for (int a = 0; a < 2; ++a)
#pragma unroll
          for (int r = 0; r < 4; ++r) {
            float v = kok ? sc[a][s][r] : -1e30f;
            sc[a][s][r] = v;
            tmax[a][r] = fmaxf(tmax[a][r], v);
          }
      }
    } else {  // diagonal tile: per-element causal mask
#pragma unroll
      for (int s = 0; s < 4; ++s) {
        int key = k0 + s * 16 + li;
        bool kok = ((kmsk >> (s * 16 + li)) & 1ull) != 0;
#pragma unroll
        for (int a = 0; a < 2; ++a)
#pragma unroll
          for (int r = 0; r < 4; ++r) {
            int q = q0 + a * 16 + g * 4 + r;
            float v = (kok && key <= q) ? sc[a][s][r] : -1e30f;
            sc[a][s][r] = v;
            tmax[a][r] = fmaxf(tmax[a][r], v);
          }
      }
    }
    // DPP 16-lane row reduce (max), then online-softmax update in exp2 domain
    float alpha[2][4];
#pragma unroll
    for (int a = 0; a < 2; ++a)
#pragma unroll
      for (int r = 0; r < 4; ++r) {
        float mn = fmaxf(mrow[a][r], rowmax16(tmax[a][r]));
        alpha[a][r] = exp2f(mrow[a][r] - mn);
        mrow[a][r] = mn;
      }
    float ps[2][4] = {};
#pragma unroll
    for (int s = 0; s < 4; ++s)
#pragma unroll
      for (int a = 0; a < 2; ++a)
#pragma unroll
        for (int r = 0; r < 4; ++r) {
          float p = exp2f(sc[a][s][r] - mrow[a][r]);  // masked -> 0
          ps[a][r] += p;
          Plds[w][a][g * 4 + r][s * 16 + li] = f2bf(p);
        }
#pragma unroll
    for (int a = 0; a < 2; ++a)
#pragma unroll
      for (int r = 0; r < 4; ++r) {
        lrow[a][r] = lrow[a][r] * alpha[a][r] + rowsum16(ps[a][r]);
#pragma unroll
        for (int ti = 0; ti < 4; ++ti) acc[a][ti][r] *= alpha[a][r];
      }
    // P A-fragments from LDS (same-wave RAW; compiler inserts waits)
    bf16x8 pf[2][2];
#pragma unroll
    for (int a = 0; a < 2; ++a)
#pragma unroll
      for (int ks = 0; ks < 2; ++ks)
        pf[a][ks] = load8(&Plds[w][a][li][ks * 32 + g * 8]);
#pragma unroll
    for (int ti = 0; ti < 4; ++ti) {
      bf16x8 vf0 = load8(Vh + (ti * 16 + li) * 2048 + k0 + 0 + g * 8);
      bf16x8 vf1 = load8(Vh + (ti * 16 + li) * 2048 + k0 + 32 + g * 8);
#pragma unroll
      for (int a = 0; a < 2; ++a) {
        acc[a][ti] = __builtin_amdgcn_mfma_f32_16x16x32_bf16(pf[a][0], vf0, acc[a][ti], 0, 0, 0);
        acc[a][ti] = __builtin_amdgcn_mfma_f32_16x16x32_bf16(pf[a][1], vf1, acc[a][ti], 0, 0, 0);
      }
    }
  }
  const int idx = (h * 64 + qb) * NCH + c;
  if (li == 0) {
#pragma unroll
    for (int a = 0; a < 2; ++a)
#pragma unroll
      for (int r = 0; r < 4; ++r) {
        Mpart[idx * 32 + a * 16 + g * 4 + r] = mrow[a][r];  // log2 domain
        Lpart[idx * 32 + a * 16 + g * 4 + r] = lrow[a][r];
      }
  }
#pragma unroll
  for (int a = 0; a < 2; ++a)
#pragma unroll
    for (int ti = 0; ti < 4; ++ti)
#pragma unroll
      for (int r = 0; r < 4; ++r)
        Opart[idx * 2048 + (a * 16 + g * 4 + r) * 64 + ti * 16 + li] = f2bf(acc[a][ti][r]);
}

// ---------------- combine partials -> Ab bf16 [s][h*64+d] (exp2 domain) ----------------
__global__ __launch_bounds__(256) void attn_combine(
    const float* __restrict__ Mpart, const float* __restrict__ Lpart,
    const u16* __restrict__ Opart, u16* __restrict__ Ab) {
  const int qb = blockIdx.x, h = blockIdx.y;  // qb: 32-row block, 0..63
  const int t = threadIdx.x;
  const int q = t >> 3, dg = t & 7;  // q 0..31, d = dg*8..dg*8+7
  const int nch = qb / 8 + 1;        // ceil((qb*32+32)/256)
  const int base = (h * 64 + qb) * NCH;
  float M = -1e30f;
#pragma unroll
  for (int c = 0; c < NCH; ++c)
    if (c < nch) M = fmaxf(M, Mpart[(base + c) * 32 + q]);
  float L = 0.f;
  float o[8] = {};
#pragma unroll
  for (int c = 0; c < NCH; ++c)
    if (c < nch) {
      float e = exp2f(Mpart[(base + c) * 32 + q] - M);
      L += e * Lpart[(base + c) * 32 + q];
      uint4 pk = *(const uint4*)(Opart + (base + c) * 2048 + q * 64 + dg * 8);
      const u16* ps = (const u16*)&pk;
#pragma unroll
      for (int jj = 0; jj < 8; ++jj) o[jj] += e * bf2f(ps[jj]);
    }
  float inv = 1.f / L;
  u16* dst = Ab + (qb * 32 + q) * 1024 + h * 64 + dg * 8;
  union { u16 s[8]; uint4 u; } ou;
#pragma unroll
  for (int jj = 0; jj < 8; ++jj) ou.s[jj] = f2bf(o[jj] * inv);
  *(uint4*)dst = ou.u;
}

extern "C" void kernel_launch(void* const* d_in, const int* in_sizes, int n_in,
                              void* d_out, int out_size, void* d_ws, size_t ws_size,
                              hipStream_t stream) {
  const float* X = (const float*)d_in[0];
  const int* amask = (const int*)d_in[1];
  const int* pos = (const int*)d_in[2];
  const float* wq = (const float*)d_in[3];
  const float* wk = (const float*)d_in[4];
  const float* wv = (const float*)d_in[5];
  const float* wo = (const float*)d_in[6];
  float* out = (float*)d_out;
  char* ws = (char*)d_ws;
  // workspace layout (~66 MB total)
  u16* Xb  = (u16*)(ws);                  // 4 MB  X bf16 [2048][1024]
  u16* Wtq = (u16*)(ws + (4u  << 20));    // 2 MB  Wt [n][k]
  u16* Wtk = (u16*)(ws + (6u  << 20));
  u16* Wtv = (u16*)(ws + (8u  << 20));
  u16* Wto = (u16*)(ws + (10u << 20));
  u16* Qb  = (u16*)(ws + (12u << 20));    // 4 MB  [2048][1024] (RoPE'd, x log2e/8)
  u16* Kb  = (u16*)(ws + (16u << 20));    // 4 MB
  u16* Vb  = (u16*)(ws + (20u << 20));    // 4 MB
  u16* Vt  = (u16*)(ws + (24u << 20));    // 4 MB  [16][64][2048]
  u16* Ab  = (u16*)(ws + (28u << 20));    // 4 MB  attn out bf16
  float* Mpart = (float*)(ws + (32u << 20));  // 1 MB  [16*64*8][32]
  float* Lpart = (float*)(ws + (33u << 20));  // 1 MB
  u16*   Opart = (u16*)(ws + (34u << 20));    // 32 MB [16*64*8][2048]

  convert_x<<<2048, 256, 0, stream>>>(X, Xb);
  transpose_w<<<dim3(16, 16, 4), 256, 0, stream>>>(wq, wk, wv, wo, Wtq, Wtk, Wtv, Wto);
  gemm_bf16<64, 128, 3, false><<<dim3(24, 32), 256, 0, stream>>>(Xb, Wtq, Wtk, Wtv, Qb, Kb, Vb, nullptr);
  rope_qk<<<4096, 256, 0, stream>>>(Qb, Kb, pos);
  v_transpose<<<dim3(32, 16), 256, 0, stream>>>(Vb, Vt);
  attn_partial<<<1152, 256, 0, stream>>>(Qb, Kb, Vt, amask, Mpart, Lpart, Opart);
  attn_combine<<<dim3(64, 16), 256, 0, stream>>>(Mpart, Lpart, Opart, Ab);
  gemm_bf16<64, 64, 1, true><<<dim3(16, 32), 256, 0, stream>>>(Ab, Wto, nullptr, nullptr,
                                                               nullptr, nullptr, nullptr, out);
}

// Round 12
// 124.798 us; speedup vs baseline: 1.4094x; 1.4094x over previous
//
#include <hip/hip_runtime.h>
#include <stdint.h>

#define SEQ 2048
#define DMODEL 1024
#define NHEAD 16
#define HDIM 64
#define KCH 256    // keys per attn work item
#define NCH 8      // max chunks per q-block (SEQ/KCH)
// q-blocks of 32 rows: 64 per head. items per head = sum_{c=0..7}(64-8c) = 288.

typedef unsigned short u16;
typedef __attribute__((ext_vector_type(4))) float f32x4;
typedef __attribute__((ext_vector_type(8))) __bf16 bf16x8;
typedef __attribute__((ext_vector_type(8))) u16 u16x8;

__device__ __forceinline__ u16 f2bf(float f) {
  unsigned int u = __builtin_bit_cast(unsigned int, f);
  unsigned int r = (u + 0x7FFFu + ((u >> 16) & 1u)) >> 16;
  return (u16)r;
}
__device__ __forceinline__ float bf2f(u16 b) {
  unsigned int u = ((unsigned int)b) << 16;
  return __builtin_bit_cast(float, u);
}
__device__ __forceinline__ bf16x8 load8(const u16* p) {
  return __builtin_bit_cast(bf16x8, *(const u16x8*)p);
}
__device__ __forceinline__ void gl_lds16(const void* g, void* l) {
  __builtin_amdgcn_global_load_lds(
      (const __attribute__((address_space(1))) unsigned int*)g,
      (__attribute__((address_space(3))) unsigned int*)l, 16, 0, 0);
}
// DPP row_ror move (16-lane row domain). CTRL = 0x120 | n.
template <int CTRL>
__device__ __forceinline__ float dpp_mv(float x) {
  return __builtin_bit_cast(float,
      __builtin_amdgcn_update_dpp(0, __builtin_bit_cast(int, x), CTRL, 0xF, 0xF, false));
}
__device__ __forceinline__ float rowmax16(float v) {
  v = fmaxf(v, dpp_mv<0x121>(v));
  v = fmaxf(v, dpp_mv<0x122>(v));
  v = fmaxf(v, dpp_mv<0x124>(v));
  v = fmaxf(v, dpp_mv<0x128>(v));
  return v;
}
__device__ __forceinline__ float rowsum16(float v) {
  v += dpp_mv<0x121>(v);
  v += dpp_mv<0x122>(v);
  v += dpp_mv<0x124>(v);
  v += dpp_mv<0x128>(v);
  return v;
}

// ---------------- f32 -> bf16 convert (hidden_states) ----------------
__global__ __launch_bounds__(256) void convert_x(const float* __restrict__ X,
                                                 u16* __restrict__ Xb) {
  int i = (blockIdx.x * 256 + threadIdx.x) * 4;
  float4 v = *(const float4*)(X + i);
  union { u16 s[4]; uint2 u; } o;
  o.s[0] = f2bf(v.x); o.s[1] = f2bf(v.y); o.s[2] = f2bf(v.z); o.s[3] = f2bf(v.w);
  *(uint2*)(Xb + i) = o.u;
}

// ------------- weight transpose+convert: W[k][n] f32 -> Wt[n][k] bf16 -------------
__global__ __launch_bounds__(256) void transpose_w(
    const float* __restrict__ W0, const float* __restrict__ W1,
    const float* __restrict__ W2, const float* __restrict__ W3,
    u16* __restrict__ T0, u16* __restrict__ T1,
    u16* __restrict__ T2, u16* __restrict__ T3) {
  __shared__ u16 tile[64][65];
  int bz = blockIdx.z;
  const float* W = bz == 0 ? W0 : bz == 1 ? W1 : bz == 2 ? W2 : W3;
  u16* T = bz == 0 ? T0 : bz == 1 ? T1 : bz == 2 ? T2 : T3;
  int n0 = blockIdx.x * 64, k0 = blockIdx.y * 64;
  int t = threadIdx.x;
#pragma unroll 4
  for (int i = 0; i < 16; ++i) {
    int idx = i * 256 + t;
    int r = idx >> 6, c = idx & 63;
    tile[r][c] = f2bf(W[(k0 + r) * 1024 + n0 + c]);
  }
  __syncthreads();
#pragma unroll 4
  for (int i = 0; i < 16; ++i) {
    int idx = i * 256 + t;
    int r = idx >> 6, c = idx & 63;  // r = n-local, c = k-local
    T[(n0 + r) * 1024 + k0 + c] = tile[c][r];
  }
}

// ---------------- bf16 MFMA GEMM: C[M][n] = A[M][K] * W[K][n], B given as Wt[n][k] ----------------
template <int BM, int BN, int NMATS, bool OUTF32>
__global__ __launch_bounds__(256) void gemm_bf16(
    const u16* __restrict__ A, const u16* __restrict__ B0,
    const u16* __restrict__ B1, const u16* __restrict__ B2,
    u16* __restrict__ O0, u16* __restrict__ O1, u16* __restrict__ O2,
    float* __restrict__ OF) {
  constexpr int MI = BM / 32, NI = BN / 32;
  constexpr int LA = BM / 64, LB = BN / 64;
  __shared__ u16 As[BM * 32];
  __shared__ u16 Bs[BN * 32];
  const int t = threadIdx.x;
  const int lane = t & 63, w = t >> 6;
  const int g = lane >> 4, li = lane & 15;
  const int n0g = blockIdx.x * BN;
  const int mat = n0g >> 10;
  const int n0 = n0g & 1023;
  const u16* Bp = (NMATS == 1 || mat == 0) ? B0 : (mat == 1 ? B1 : B2);
  const int m0 = blockIdx.y * BM;
  const int wm = (w >> 1) * (BM / 2), wn = (w & 1) * (BN / 2);
  f32x4 acc[MI][NI] = {};
  for (int k0 = 0; k0 < 1024; k0 += 32) {
#pragma unroll
    for (int it = 0; it < LA; ++it) {
      int L = it * 2048 + t * 8;
      int r = L >> 5, c = L & 31;
      gl_lds16(A + (m0 + r) * 1024 + k0 + c, (char*)As + it * 4096 + w * 1024);
    }
#pragma unroll
    for (int it = 0; it < LB; ++it) {
      int L = it * 2048 + t * 8;
      int r = L >> 5, c = L & 31;
      gl_lds16(Bp + (n0 + r) * 1024 + k0 + c, (char*)Bs + it * 4096 + w * 1024);
    }
    __syncthreads();
    bf16x8 af[MI], bfr[NI];
#pragma unroll
    for (int mi = 0; mi < MI; ++mi) af[mi] = load8(&As[(wm + mi * 16 + li) * 32 + g * 8]);
#pragma unroll
    for (int ni = 0; ni < NI; ++ni) bfr[ni] = load8(&Bs[(wn + ni * 16 + li) * 32 + g * 8]);
#pragma unroll
    for (int mi = 0; mi < MI; ++mi)
#pragma unroll
      for (int ni = 0; ni < NI; ++ni)
        acc[mi][ni] = __builtin_amdgcn_mfma_f32_16x16x32_bf16(af[mi], bfr[ni], acc[mi][ni], 0, 0, 0);
    __syncthreads();
  }
  u16* Ob = (NMATS == 1 || mat == 0) ? O0 : (mat == 1 ? O1 : O2);
#pragma unroll
  for (int mi = 0; mi < MI; ++mi)
#pragma unroll
    for (int ni = 0; ni < NI; ++ni)
#pragma unroll
      for (int r = 0; r < 4; ++r) {
        // verified C/D layout: row = (lane>>4)*4 + r, col = lane&15
        int m = m0 + wm + mi * 16 + g * 4 + r;
        int n = n0 + wn + ni * 16 + li;
        float v = acc[mi][ni][r];
        if (OUTF32) OF[m * 1024 + n] = v;
        else Ob[m * 1024 + n] = f2bf(v);
      }
}

// ------- RoPE in-place on bf16 Q,K; fold 1/sqrt(HD) AND log2(e) into Q (exp2-domain softmax) -------
__global__ __launch_bounds__(256) void rope_qk(u16* __restrict__ Qb, u16* __restrict__ Kb,
                                               const int* __restrict__ pos_ids) {
  int gid = blockIdx.x * 256 + threadIdx.x;  // one per (s,h,pair)
  int s = gid >> 9;
  int rem = gid & 511;
  int h = rem >> 5, i = rem & 31;
  float pos = (float)pos_ids[s];
  float inv = exp2f(-(float)i * (13.287712379549449f / 32.0f));
  float ang = pos * inv;
  float sn, cs;
  sincosf(ang, &sn, &cs);
  int base = s * 1024 + h * 64 + 2 * i;
  const float qs = 0.125f * 1.4426950408889634f;  // 1/sqrt(64) * log2(e)
  {
    float x0 = bf2f(Qb[base]), x1 = bf2f(Qb[base + 1]);
    Qb[base]     = f2bf((x0 * cs - x1 * sn) * qs);
    Qb[base + 1] = f2bf((x0 * sn + x1 * cs) * qs);
  }
  {
    float x0 = bf2f(Kb[base]), x1 = bf2f(Kb[base + 1]);
    Kb[base]     = f2bf(x0 * cs - x1 * sn);
    Kb[base + 1] = f2bf(x0 * sn + x1 * cs);
  }
}

// ---------------- V transpose: Vb[s][h*64+d] -> Vt[h][d][s] ----------------
__global__ __launch_bounds__(256) void v_transpose(const u16* __restrict__ Vb,
                                                   u16* __restrict__ Vt) {
  __shared__ u16 tile[64][65];
  const int t = threadIdx.x;
  const int s0 = blockIdx.x * 64, h = blockIdx.y;
#pragma unroll 4
  for (int i = 0; i < 16; ++i) {
    int idx = i * 256 + t;
    int r = idx >> 6, c = idx & 63;
    tile[r][c] = Vb[(s0 + r) * 1024 + h * 64 + c];
  }
  __syncthreads();
#pragma unroll 4
  for (int i = 0; i < 16; ++i) {
    int idx = i * 256 + t;
    int d = idx >> 6, sc = idx & 63;
    Vt[h * (64 * 2048) + d * 2048 + s0 + sc] = tile[sc][d];
  }
}

// ---------------- split-K flash attention partial: QBLK=32, KVBLK=64, KCH=256 ----------------
// 1152 blocks x 4 waves = 288 waves/head = exactly 1 item per wave, max 4 iterations.
// NO min-waves clause: round 11 showed __launch_bounds__(256,5) forces VGPR=48 + scratch
// spills (271 MB writes/dispatch, 2.3x regression). Compiler lands ~84-128 VGPR -> 4-6
// blocks/CU resident naturally.
// head = bid & 15 -> one XCD per head (1152 % 16 == 0), K/V stay L2-hot.
// DPP row_ror 16-lane reduce (no LDS traffic); exp2-domain scores (Q pre-scaled by log2 e).
__global__ __launch_bounds__(256) void attn_partial(
    const u16* __restrict__ Qb, const u16* __restrict__ Kb,
    const u16* __restrict__ Vt, const int* __restrict__ amask,
    float* __restrict__ Mpart, float* __restrict__ Lpart, u16* __restrict__ Opart) {
  const int t = threadIdx.x, lane = t & 63, w = t >> 6;
  const int g = lane >> 4, li = lane & 15;
  const int bid = blockIdx.x;
  const int h = bid & 15;
  const int j = (bid >> 4) * 4 + w;  // 0..287
  __shared__ u16 Plds[4][2][16][72];  // per-wave P tile [a][q16][64+8pad]
  const u16* Vh = Vt + h * (64 * 2048);
  // decode chunk c, q-block qb (32 rows); segment starts S_c = 64c - 4c(c-1)
  // = {0, 64, 120, 168, 208, 240, 264, 280}
  const int c = (j >= 280) ? 7 : (j >= 264) ? 6 : (j >= 240) ? 5 : (j >= 208) ? 4
              : (j >= 168) ? 3 : (j >= 120) ? 2 : (j >= 64) ? 1 : 0;
  const int qb = 8 * c + (j - (64 * c - 4 * c * (c - 1)));
  const int q0 = qb * 32;
  const int kstart = c * KCH;
  const int kend = min(kstart + KCH, q0 + 32);
  bf16x8 qf[2][2];
#pragma unroll
  for (int a = 0; a < 2; ++a)
#pragma unroll
    for (int hf = 0; hf < 2; ++hf)
      qf[a][hf] = load8(Qb + (q0 + a * 16 + li) * 1024 + h * 64 + hf * 32 + g * 8);
  f32x4 acc[2][4] = {};
  float mrow[2][4], lrow[2][4];
#pragma unroll
  for (int a = 0; a < 2; ++a)
#pragma unroll
    for (int r = 0; r < 4; ++r) { mrow[a][r] = -1e30f; lrow[a][r] = 0.f; }
  for (int k0 = kstart; k0 < kend; k0 += 64) {
    // padding mask for this 64-key tile: 1 load + ballot (k0+lane <= 2047 always)
    unsigned long long kmsk = __ballot(amask[k0 + lane] != 0);
    f32x4 sc[2][4] = {};
#pragma unroll
    for (int s = 0; s < 4; ++s) {
      bf16x8 kf0 = load8(Kb + (k0 + s * 16 + li) * 1024 + h * 64 + 0 + g * 8);
      bf16x8 kf1 = load8(Kb + (k0 + s * 16 + li) * 1024 + h * 64 + 32 + g * 8);
#pragma unroll
      for (int a = 0; a < 2; ++a) {
        sc[a][s] = __builtin_amdgcn_mfma_f32_16x16x32_bf16(qf[a][0], kf0, sc[a][s], 0, 0, 0);
        sc[a][s] = __builtin_amdgcn_mfma_f32_16x16x32_bf16(qf[a][1], kf1, sc[a][s], 0, 0, 0);
      }
    }
    // mask in place + in-lane fold over the 4 key-subtiles.
    // Score layout: q = a*16 + g*4 + r, key = s*16 + li.
    float tmax[2][4];
#pragma unroll
    for (int a = 0; a < 2; ++a)
#pragma unroll
      for (int r = 0; r < 4; ++r) tmax[a][r] = -1e30f;
    if (k0 + 63 <= q0) {  // full tile: causal always satisfied (wave-uniform branch)
#pragma unroll
      for (int s = 0; s < 4; ++s) {
        bool kok = ((kmsk >> (s * 16 + li)) & 1ull) != 0;
#pragma unroll
        for (int a = 0; a < 2; ++a)
#pragma unroll
          for (int r = 0; r < 4; ++r) {
            float v = kok ? sc[a][s][r] : -1e30f;
            sc[a][s][r] = v;
            tmax[a][r] = fmaxf(tmax[a][r], v);
          }
      }
    } else {  // diagonal tile: per-element causal mask
#pragma unroll
      for (int s = 0; s < 4; ++s) {
        int key = k0 + s * 16 + li;
        bool kok = ((kmsk >> (s * 16 + li)) & 1ull) != 0;
#pragma unroll
        for (int a = 0; a < 2; ++a)
#pragma unroll
          for (int r = 0; r < 4; ++r) {
            int q = q0 + a * 16 + g * 4 + r;
            float v = (kok && key <= q) ? sc[a][s][r] : -1e30f;
            sc[a][s][r] = v;
            tmax[a][r] = fmaxf(tmax[a][r], v);
          }
      }
    }
    // DPP 16-lane row reduce (max), then online-softmax update in exp2 domain
    float alpha[2][4];
#pragma unroll
    for (int a = 0; a < 2; ++a)
#pragma unroll
      for (int r = 0; r < 4; ++r) {
        float mn = fmaxf(mrow[a][r], rowmax16(tmax[a][r]));
        alpha[a][r] = exp2f(mrow[a][r] - mn);
        mrow[a][r] = mn;
      }
    float ps[2][4] = {};
#pragma unroll
    for (int s = 0; s < 4; ++s)
#pragma unroll
      for (int a = 0; a < 2; ++a)
#pragma unroll
        for (int r = 0; r < 4; ++r) {
          float p = exp2f(sc[a][s][r] - mrow[a][r]);  // masked -> 0
          ps[a][r] += p;
          Plds[w][a][g * 4 + r][s * 16 + li] = f2bf(p);
        }
#pragma unroll
    for (int a = 0; a < 2; ++a)
#pragma unroll
      for (int r = 0; r < 4; ++r) {
        lrow[a][r] = lrow[a][r] * alpha[a][r] + rowsum16(ps[a][r]);
#pragma unroll
        for (int ti = 0; ti < 4; ++ti) acc[a][ti][r] *= alpha[a][r];
      }
    // P A-fragments from LDS (same-wave RAW; compiler inserts waits)
    bf16x8 pf[2][2];
#pragma unroll
    for (int a = 0; a < 2; ++a)
#pragma unroll
      for (int ks = 0; ks < 2; ++ks)
        pf[a][ks] = load8(&Plds[w][a][li][ks * 32 + g * 8]);
#pragma unroll
    for (int ti = 0; ti < 4; ++ti) {
      bf16x8 vf0 = load8(Vh + (ti * 16 + li) * 2048 + k0 + 0 + g * 8);
      bf16x8 vf1 = load8(Vh + (ti * 16 + li) * 2048 + k0 + 32 + g * 8);
#pragma unroll
      for (int a = 0; a < 2; ++a) {
        acc[a][ti] = __builtin_amdgcn_mfma_f32_16x16x32_bf16(pf[a][0], vf0, acc[a][ti], 0, 0, 0);
        acc[a][ti] = __builtin_amdgcn_mfma_f32_16x16x32_bf16(pf[a][1], vf1, acc[a][ti], 0, 0, 0);
      }
    }
  }
  const int idx = (h * 64 + qb) * NCH + c;
  if (li == 0) {
#pragma unroll
    for (int a = 0; a < 2; ++a)
#pragma unroll
      for (int r = 0; r < 4; ++r) {
        Mpart[idx * 32 + a * 16 + g * 4 + r] = mrow[a][r];  // log2 domain
        Lpart[idx * 32 + a * 16 + g * 4 + r] = lrow[a][r];
      }
  }
#pragma unroll
  for (int a = 0; a < 2; ++a)
#pragma unroll
    for (int ti = 0; ti < 4; ++ti)
#pragma unroll
      for (int r = 0; r < 4; ++r)
        Opart[idx * 2048 + (a * 16 + g * 4 + r) * 64 + ti * 16 + li] = f2bf(acc[a][ti][r]);
}

// ---------------- combine partials -> Ab bf16 [s][h*64+d] (exp2 domain) ----------------
__global__ __launch_bounds__(256) void attn_combine(
    const float* __restrict__ Mpart, const float* __restrict__ Lpart,
    const u16* __restrict__ Opart, u16* __restrict__ Ab) {
  const int qb = blockIdx.x, h = blockIdx.y;  // qb: 32-row block, 0..63
  const int t = threadIdx.x;
  const int q = t >> 3, dg = t & 7;  // q 0..31, d = dg*8..dg*8+7
  const int nch = qb / 8 + 1;        // ceil((qb*32+32)/256)
  const int base = (h * 64 + qb) * NCH;
  float M = -1e30f;
#pragma unroll
  for (int c = 0; c < NCH; ++c)
    if (c < nch) M = fmaxf(M, Mpart[(base + c) * 32 + q]);
  float L = 0.f;
  float o[8] = {};
#pragma unroll
  for (int c = 0; c < NCH; ++c)
    if (c < nch) {
      float e = exp2f(Mpart[(base + c) * 32 + q] - M);
      L += e * Lpart[(base + c) * 32 + q];
      uint4 pk = *(const uint4*)(Opart + (base + c) * 2048 + q * 64 + dg * 8);
      const u16* ps = (const u16*)&pk;
#pragma unroll
      for (int jj = 0; jj < 8; ++jj) o[jj] += e * bf2f(ps[jj]);
    }
  float inv = 1.f / L;
  u16* dst = Ab + (qb * 32 + q) * 1024 + h * 64 + dg * 8;
  union { u16 s[8]; uint4 u; } ou;
#pragma unroll
  for (int jj = 0; jj < 8; ++jj) ou.s[jj] = f2bf(o[jj] * inv);
  *(uint4*)dst = ou.u;
}

extern "C" void kernel_launch(void* const* d_in, const int* in_sizes, int n_in,
                              void* d_out, int out_size, void* d_ws, size_t ws_size,
                              hipStream_t stream) {
  const float* X = (const float*)d_in[0];
  const int* amask = (const int*)d_in[1];
  const int* pos = (const int*)d_in[2];
  const float* wq = (const float*)d_in[3];
  const float* wk = (const float*)d_in[4];
  const float* wv = (const float*)d_in[5];
  const float* wo = (const float*)d_in[6];
  float* out = (float*)d_out;
  char* ws = (char*)d_ws;
  // workspace layout (~66 MB total)
  u16* Xb  = (u16*)(ws);                  // 4 MB  X bf16 [2048][1024]
  u16* Wtq = (u16*)(ws + (4u  << 20));    // 2 MB  Wt [n][k]
  u16* Wtk = (u16*)(ws + (6u  << 20));
  u16* Wtv = (u16*)(ws + (8u  << 20));
  u16* Wto = (u16*)(ws + (10u << 20));
  u16* Qb  = (u16*)(ws + (12u << 20));    // 4 MB  [2048][1024] (RoPE'd, x log2e/8)
  u16* Kb  = (u16*)(ws + (16u << 20));    // 4 MB
  u16* Vb  = (u16*)(ws + (20u << 20));    // 4 MB
  u16* Vt  = (u16*)(ws + (24u << 20));    // 4 MB  [16][64][2048]
  u16* Ab  = (u16*)(ws + (28u << 20));    // 4 MB  attn out bf16
  float* Mpart = (float*)(ws + (32u << 20));  // 1 MB  [16*64*8][32]
  float* Lpart = (float*)(ws + (33u << 20));  // 1 MB
  u16*   Opart = (u16*)(ws + (34u << 20));    // 32 MB [16*64*8][2048]

  convert_x<<<2048, 256, 0, stream>>>(X, Xb);
  transpose_w<<<dim3(16, 16, 4), 256, 0, stream>>>(wq, wk, wv, wo, Wtq, Wtk, Wtv, Wto);
  gemm_bf16<64, 128, 3, false><<<dim3(24, 32), 256, 0, stream>>>(Xb, Wtq, Wtk, Wtv, Qb, Kb, Vb, nullptr);
  rope_qk<<<4096, 256, 0, stream>>>(Qb, Kb, pos);
  v_transpose<<<dim3(32, 16), 256, 0, stream>>>(Vb, Vt);
  attn_partial<<<1152, 256, 0, stream>>>(Qb, Kb, Vt, amask, Mpart, Lpart, Opart);
  attn_combine<<<dim3(64, 16), 256, 0, stream>>>(Mpart, Lpart, Opart, Ab);
  gemm_bf16<64, 64, 1, true><<<dim3(16, 32), 256, 0, stream>>>(Ab, Wto, nullptr, nullptr,
                                                               nullptr, nullptr, nullptr, out);
}

// Round 13
// 119.982 us; speedup vs baseline: 1.4660x; 1.0401x over previous
//
#include <hip/hip_runtime.h>
#include <stdint.h>

#define SEQ 2048
#define DMODEL 1024
#define NHEAD 16
#define HDIM 64
#define KCH 256    // keys per attn work item
#define NCH 8      // max chunks per q-block (SEQ/KCH)
// q-blocks of 32 rows: 64 per head. items per head = sum_{c=0..7}(64-8c) = 288.

typedef unsigned short u16;
typedef __attribute__((ext_vector_type(4))) float f32x4;
typedef __attribute__((ext_vector_type(16))) float f32x16;
typedef __attribute__((ext_vector_type(8))) __bf16 bf16x8;
typedef __attribute__((ext_vector_type(8))) u16 u16x8;

__device__ __forceinline__ u16 f2bf(float f) {
  unsigned int u = __builtin_bit_cast(unsigned int, f);
  unsigned int r = (u + 0x7FFFu + ((u >> 16) & 1u)) >> 16;
  return (u16)r;
}
__device__ __forceinline__ float bf2f(u16 b) {
  unsigned int u = ((unsigned int)b) << 16;
  return __builtin_bit_cast(float, u);
}
__device__ __forceinline__ bf16x8 load8(const u16* p) {
  return __builtin_bit_cast(bf16x8, *(const u16x8*)p);
}
__device__ __forceinline__ void gl_lds16(const void* g, void* l) {
  __builtin_amdgcn_global_load_lds(
      (const __attribute__((address_space(1))) unsigned int*)g,
      (__attribute__((address_space(3))) unsigned int*)l, 16, 0, 0);
}

// ---------------- f32 -> bf16 convert (hidden_states) ----------------
__global__ __launch_bounds__(256) void convert_x(const float* __restrict__ X,
                                                 u16* __restrict__ Xb) {
  int i = (blockIdx.x * 256 + threadIdx.x) * 4;
  float4 v = *(const float4*)(X + i);
  union { u16 s[4]; uint2 u; } o;
  o.s[0] = f2bf(v.x); o.s[1] = f2bf(v.y); o.s[2] = f2bf(v.z); o.s[3] = f2bf(v.w);
  *(uint2*)(Xb + i) = o.u;
}

// ------------- weight transpose+convert: W[k][n] f32 -> Wt[n][k] bf16 -------------
__global__ __launch_bounds__(256) void transpose_w(
    const float* __restrict__ W0, const float* __restrict__ W1,
    const float* __restrict__ W2, const float* __restrict__ W3,
    u16* __restrict__ T0, u16* __restrict__ T1,
    u16* __restrict__ T2, u16* __restrict__ T3) {
  __shared__ u16 tile[64][65];
  int bz = blockIdx.z;
  const float* W = bz == 0 ? W0 : bz == 1 ? W1 : bz == 2 ? W2 : W3;
  u16* T = bz == 0 ? T0 : bz == 1 ? T1 : bz == 2 ? T2 : T3;
  int n0 = blockIdx.x * 64, k0 = blockIdx.y * 64;
  int t = threadIdx.x;
#pragma unroll 4
  for (int i = 0; i < 16; ++i) {
    int idx = i * 256 + t;
    int r = idx >> 6, c = idx & 63;
    tile[r][c] = f2bf(W[(k0 + r) * 1024 + n0 + c]);
  }
  __syncthreads();
#pragma unroll 4
  for (int i = 0; i < 16; ++i) {
    int idx = i * 256 + t;
    int r = idx >> 6, c = idx & 63;  // r = n-local, c = k-local
    T[(n0 + r) * 1024 + k0 + c] = tile[c][r];
  }
}

// ---------------- bf16 MFMA GEMM: C[M][n] = A[M][K] * W[K][n], B given as Wt[n][k] ----------------
template <int BM, int BN, int NMATS, bool OUTF32>
__global__ __launch_bounds__(256) void gemm_bf16(
    const u16* __restrict__ A, const u16* __restrict__ B0,
    const u16* __restrict__ B1, const u16* __restrict__ B2,
    u16* __restrict__ O0, u16* __restrict__ O1, u16* __restrict__ O2,
    float* __restrict__ OF) {
  constexpr int MI = BM / 32, NI = BN / 32;
  constexpr int LA = BM / 64, LB = BN / 64;
  __shared__ u16 As[BM * 32];
  __shared__ u16 Bs[BN * 32];
  const int t = threadIdx.x;
  const int lane = t & 63, w = t >> 6;
  const int g = lane >> 4, li = lane & 15;
  const int n0g = blockIdx.x * BN;
  const int mat = n0g >> 10;
  const int n0 = n0g & 1023;
  const u16* Bp = (NMATS == 1 || mat == 0) ? B0 : (mat == 1 ? B1 : B2);
  const int m0 = blockIdx.y * BM;
  const int wm = (w >> 1) * (BM / 2), wn = (w & 1) * (BN / 2);
  f32x4 acc[MI][NI] = {};
  for (int k0 = 0; k0 < 1024; k0 += 32) {
#pragma unroll
    for (int it = 0; it < LA; ++it) {
      int L = it * 2048 + t * 8;
      int r = L >> 5, c = L & 31;
      gl_lds16(A + (m0 + r) * 1024 + k0 + c, (char*)As + it * 4096 + w * 1024);
    }
#pragma unroll
    for (int it = 0; it < LB; ++it) {
      int L = it * 2048 + t * 8;
      int r = L >> 5, c = L & 31;
      gl_lds16(Bp + (n0 + r) * 1024 + k0 + c, (char*)Bs + it * 4096 + w * 1024);
    }
    __syncthreads();
    bf16x8 af[MI], bfr[NI];
#pragma unroll
    for (int mi = 0; mi < MI; ++mi) af[mi] = load8(&As[(wm + mi * 16 + li) * 32 + g * 8]);
#pragma unroll
    for (int ni = 0; ni < NI; ++ni) bfr[ni] = load8(&Bs[(wn + ni * 16 + li) * 32 + g * 8]);
#pragma unroll
    for (int mi = 0; mi < MI; ++mi)
#pragma unroll
      for (int ni = 0; ni < NI; ++ni)
        acc[mi][ni] = __builtin_amdgcn_mfma_f32_16x16x32_bf16(af[mi], bfr[ni], acc[mi][ni], 0, 0, 0);
    __syncthreads();
  }
  u16* Ob = (NMATS == 1 || mat == 0) ? O0 : (mat == 1 ? O1 : O2);
#pragma unroll
  for (int mi = 0; mi < MI; ++mi)
#pragma unroll
    for (int ni = 0; ni < NI; ++ni)
#pragma unroll
      for (int r = 0; r < 4; ++r) {
        // verified C/D layout: row = (lane>>4)*4 + r, col = lane&15
        int m = m0 + wm + mi * 16 + g * 4 + r;
        int n = n0 + wn + ni * 16 + li;
        float v = acc[mi][ni][r];
        if (OUTF32) OF[m * 1024 + n] = v;
        else Ob[m * 1024 + n] = f2bf(v);
      }
}

// ------- RoPE in-place on bf16 Q,K; fold 1/sqrt(HD) AND log2(e) into Q (exp2-domain softmax) -------
__global__ __launch_bounds__(256) void rope_qk(u16* __restrict__ Qb, u16* __restrict__ Kb,
                                               const int* __restrict__ pos_ids) {
  int gid = blockIdx.x * 256 + threadIdx.x;  // one per (s,h,pair)
  int s = gid >> 9;
  int rem = gid & 511;
  int h = rem >> 5, i = rem & 31;
  float pos = (float)pos_ids[s];
  float inv = exp2f(-(float)i * (13.287712379549449f / 32.0f));
  float ang = pos * inv;
  float sn, cs;
  sincosf(ang, &sn, &cs);
  int base = s * 1024 + h * 64 + 2 * i;
  const float qs = 0.125f * 1.4426950408889634f;  // 1/sqrt(64) * log2(e)
  {
    float x0 = bf2f(Qb[base]), x1 = bf2f(Qb[base + 1]);
    Qb[base]     = f2bf((x0 * cs - x1 * sn) * qs);
    Qb[base + 1] = f2bf((x0 * sn + x1 * cs) * qs);
  }
  {
    float x0 = bf2f(Kb[base]), x1 = bf2f(Kb[base + 1]);
    Kb[base]     = f2bf(x0 * cs - x1 * sn);
    Kb[base + 1] = f2bf(x0 * sn + x1 * cs);
  }
}

// ---------------- V transpose: Vb[s][h*64+d] -> Vt[h][d][s] ----------------
__global__ __launch_bounds__(256) void v_transpose(const u16* __restrict__ Vb,
                                                   u16* __restrict__ Vt) {
  __shared__ u16 tile[64][65];
  const int t = threadIdx.x;
  const int s0 = blockIdx.x * 64, h = blockIdx.y;
#pragma unroll 4
  for (int i = 0; i < 16; ++i) {
    int idx = i * 256 + t;
    int r = idx >> 6, c = idx & 63;
    tile[r][c] = Vb[(s0 + r) * 1024 + h * 64 + c];
  }
  __syncthreads();
#pragma unroll 4
  for (int i = 0; i < 16; ++i) {
    int idx = i * 256 + t;
    int d = idx >> 6, sc = idx & 63;
    Vt[h * (64 * 2048) + d * 2048 + s0 + sc] = tile[sc][d];
  }
}

// -------- split-K flash attention partial: swapped QK^T, zero-LDS inner loop --------
// 1152 blocks x 4 waves, 1 item/wave (head, 32-q-block, 256-key chunk); head=bid&15
// -> one XCD per head, K/V L2-hot. Per 32-key tile:
//   S^T = mfma_32x32x16(A=K, B=Q) x4 d-slices: lane owns q=lane&31, 16 keys in regs
//   (row = (reg&3)+8*(reg>>2)+4*(lane>>5) — HW-verified C layout).
//   Softmax: in-lane fold + ONE shfl_xor(32) partner exchange. No LDS, no DPP trees.
//   P packed to bf16 in-reg; partner half fetched via 8 shfl_xor(32); PV B-fragments
//   assembled with cndmask selects; O^T += mfma(A=V^T from d-major Vt, B=P^T).
__global__ __launch_bounds__(256) void attn_partial(
    const u16* __restrict__ Qb, const u16* __restrict__ Kb,
    const u16* __restrict__ Vt, const int* __restrict__ amask,
    float* __restrict__ Mpart, float* __restrict__ Lpart, u16* __restrict__ Opart) {
  const int t = threadIdx.x, lane = t & 63, w = t >> 6;
  const int l31 = lane & 31;
  const int hi = lane >> 5;      // 0 = lower half, 1 = upper half
  const int hi4 = hi * 4;
  const int bid = blockIdx.x;
  const int h = bid & 15;
  const int j = (bid >> 4) * 4 + w;  // 0..287
  // decode chunk c, q-block qb (32 rows); segment starts S_c = 64c - 4c(c-1)
  const int c = (j >= 280) ? 7 : (j >= 264) ? 6 : (j >= 240) ? 5 : (j >= 208) ? 4
              : (j >= 168) ? 3 : (j >= 120) ? 2 : (j >= 64) ? 1 : 0;
  const int qb = 8 * c + (j - (64 * c - 4 * c * (c - 1)));
  const int q0 = qb * 32;
  const int kstart = c * KCH;
  const int kend = min(kstart + KCH, q0 + 32);
  const u16* Vh = Vt + h * (64 * 2048);
  // Q B-fragments (fixed per item): B[kk=d-slice][col=q]: col=l31, kk=hi*8+0..7
  bf16x8 qf[4];
#pragma unroll
  for (int d16 = 0; d16 < 4; ++d16)
    qf[d16] = load8(Qb + (q0 + l31) * 1024 + h * 64 + d16 * 16 + hi * 8);
  f32x16 acc0 = {}, acc1 = {};   // O^T d-tiles [0..31], [32..63]; col=q=l31
  float m = -1e30f, lsum = 0.f;  // per-lane = per-q (both halves duplicate)
  for (int k0 = kstart; k0 < kend; k0 += 32) {
    // padding bitmap for keys k0..k0+31 (bit j = amask[k0+j])
    unsigned int kmsk = (unsigned int)__ballot(amask[k0 + l31] != 0);
    // QK^T: S^T[key][q] accumulated over 4 d-slices. A=K: row=key=l31, kk=hi*8+0..7
    f32x16 s = {};
#pragma unroll
    for (int d16 = 0; d16 < 4; ++d16) {
      bf16x8 kf = load8(Kb + (k0 + l31) * 1024 + h * 64 + d16 * 16 + hi * 8);
      s = __builtin_amdgcn_mfma_f32_32x32x16_bf16(kf, qf[d16], s, 0, 0, 0);
    }
    // mask + in-lane max. reg i -> key offset (i&3)+8*(i>>2)+hi4, q = q0+l31.
    float sv[16];
    float tmax = -1e30f;
    if (k0 < q0 && kmsk == 0xFFFFFFFFu) {  // full causal tile, no padding: no masking
#pragma unroll
      for (int i = 0; i < 16; ++i) { sv[i] = s[i]; tmax = fmaxf(tmax, s[i]); }
    } else {
      const int qrel = q0 + l31 - k0 - hi4;      // valid iff koff_lo <= qrel
      const unsigned int mk = kmsk >> hi4;
#pragma unroll
      for (int i = 0; i < 16; ++i) {
        const int koff = (i & 3) + 8 * (i >> 2);  // lower-half key offset
        bool ok = (((mk >> koff) & 1u) != 0u) && (koff <= qrel);
        float v = ok ? s[i] : -1e30f;
        sv[i] = v;
        tmax = fmaxf(tmax, v);
      }
    }
    // full 32-key row max: in-lane fold done, + one partner exchange
    float pmax = fmaxf(tmax, __shfl_xor(tmax, 32, 64));
    float mn = fmaxf(m, pmax);
    float alpha = exp2f(m - mn);
    m = mn;
    float p[16];
    float ps = 0.f;
#pragma unroll
    for (int i = 0; i < 16; ++i) { p[i] = exp2f(sv[i] - mn); ps += p[i]; }
    ps += __shfl_xor(ps, 32, 64);
    lsum = lsum * alpha + ps;
    acc0 *= alpha;
    acc1 *= alpha;
    // pack P (ascending key order within lane: reg i is lane's i-th key)
    unsigned int pk[8], ot[8];
#pragma unroll
    for (int jj = 0; jj < 8; ++jj)
      pk[jj] = (unsigned int)f2bf(p[2 * jj]) | ((unsigned int)f2bf(p[2 * jj + 1]) << 16);
#pragma unroll
    for (int jj = 0; jj < 8; ++jj) ot[jj] = __shfl_xor(pk[jj], 32, 64);
    // PV B-fragments: B[kk][q], lane supplies kk=hi*8+0..7 of q=l31.
    // lower keys {0..3,8..11,16..19,24..27} = pk, upper {4..7,...} = ot (and vice versa)
    union { unsigned int u[4]; bf16x8 v; } f1, f2;
    f1.u[0] = hi ? ot[2] : pk[0];  // keys {0,1} / {8,9}
    f1.u[1] = hi ? ot[3] : pk[1];  // keys {2,3} / {10,11}
    f1.u[2] = hi ? pk[2] : ot[0];  // keys {4,5} / {12,13}
    f1.u[3] = hi ? pk[3] : ot[1];  // keys {6,7} / {14,15}
    f2.u[0] = hi ? ot[6] : pk[4];  // keys {16,17} / {24,25}
    f2.u[1] = hi ? ot[7] : pk[5];  // keys {18,19} / {26,27}
    f2.u[2] = hi ? pk[6] : ot[4];  // keys {20,21} / {28,29}
    f2.u[3] = hi ? pk[7] : ot[5];  // keys {22,23} / {30,31}
    // O^T += V^T * P^T. A=V^T: row=d_local=l31, kk=hi*8+0..7 (d-major Vt: load8 in s)
    {
      bf16x8 va = load8(Vh + (0 + l31) * 2048 + k0 + hi * 8);
      bf16x8 vb = load8(Vh + (0 + l31) * 2048 + k0 + 16 + hi * 8);
      acc0 = __builtin_amdgcn_mfma_f32_32x32x16_bf16(va, f1.v, acc0, 0, 0, 0);
      acc0 = __builtin_amdgcn_mfma_f32_32x32x16_bf16(vb, f2.v, acc0, 0, 0, 0);
    }
    {
      bf16x8 va = load8(Vh + (32 + l31) * 2048 + k0 + hi * 8);
      bf16x8 vb = load8(Vh + (32 + l31) * 2048 + k0 + 16 + hi * 8);
      acc1 = __builtin_amdgcn_mfma_f32_32x32x16_bf16(va, f1.v, acc1, 0, 0, 0);
      acc1 = __builtin_amdgcn_mfma_f32_32x32x16_bf16(vb, f2.v, acc1, 0, 0, 0);
    }
  }
  const int idx = (h * 64 + qb) * NCH + c;
  if (hi == 0) {
    Mpart[idx * 32 + l31] = m;     // log2 domain
    Lpart[idx * 32 + l31] = lsum;
  }
  // O^T writeback: acc{dt}[reg] = O[q=l31][d = dt*32 + (reg&3)+8*(reg>>2)+hi4]
  u16* outp = Opart + idx * 2048 + l31 * 64;
#pragma unroll
  for (int grp = 0; grp < 4; ++grp) {
    union { u16 s4[4]; uint2 u; } o0, o1;
#pragma unroll
    for (int r = 0; r < 4; ++r) {
      o0.s4[r] = f2bf(acc0[grp * 4 + r]);
      o1.s4[r] = f2bf(acc1[grp * 4 + r]);
    }
    *(uint2*)(outp + grp * 8 + hi4) = o0.u;
    *(uint2*)(outp + 32 + grp * 8 + hi4) = o1.u;
  }
}

// ---------------- combine partials -> Ab bf16 [s][h*64+d] (exp2 domain) ----------------
__global__ __launch_bounds__(256) void attn_combine(
    const float* __restrict__ Mpart, const float* __restrict__ Lpart,
    const u16* __restrict__ Opart, u16* __restrict__ Ab) {
  const int qb = blockIdx.x, h = blockIdx.y;  // qb: 32-row block, 0..63
  const int t = threadIdx.x;
  const int q = t >> 3, dg = t & 7;  // q 0..31, d = dg*8..dg*8+7
  const int nch = qb / 8 + 1;        // ceil((qb*32+32)/256)
  const int base = (h * 64 + qb) * NCH;
  float M = -1e30f;
#pragma unroll
  for (int c = 0; c < NCH; ++c)
    if (c < nch) M = fmaxf(M, Mpart[(base + c) * 32 + q]);
  float L = 0.f;
  float o[8] = {};
#pragma unroll
  for (int c = 0; c < NCH; ++c)
    if (c < nch) {
      float e = exp2f(Mpart[(base + c) * 32 + q] - M);
      L += e * Lpart[(base + c) * 32 + q];
      uint4 pk = *(const uint4*)(Opart + (base + c) * 2048 + q * 64 + dg * 8);
      const u16* ps = (const u16*)&pk;
#pragma unroll
      for (int jj = 0; jj < 8; ++jj) o[jj] += e * bf2f(ps[jj]);
    }
  float inv = 1.f / L;
  u16* dst = Ab + (qb * 32 + q) * 1024 + h * 64 + dg * 8;
  union { u16 s[8]; uint4 u; } ou;
#pragma unroll
  for (int jj = 0; jj < 8; ++jj) ou.s[jj] = f2bf(o[jj] * inv);
  *(uint4*)dst = ou.u;
}

extern "C" void kernel_launch(void* const* d_in, const int* in_sizes, int n_in,
                              void* d_out, int out_size, void* d_ws, size_t ws_size,
                              hipStream_t stream) {
  const float* X = (const float*)d_in[0];
  const int* amask = (const int*)d_in[1];
  const int* pos = (const int*)d_in[2];
  const float* wq = (const float*)d_in[3];
  const float* wk = (const float*)d_in[4];
  const float* wv = (const float*)d_in[5];
  const float* wo = (const float*)d_in[6];
  float* out = (float*)d_out;
  char* ws = (char*)d_ws;
  // workspace layout (~66 MB total)
  u16* Xb  = (u16*)(ws);                  // 4 MB  X bf16 [2048][1024]
  u16* Wtq = (u16*)(ws + (4u  << 20));    // 2 MB  Wt [n][k]
  u16* Wtk = (u16*)(ws + (6u  << 20));
  u16* Wtv = (u16*)(ws + (8u  << 20));
  u16* Wto = (u16*)(ws + (10u << 20));
  u16* Qb  = (u16*)(ws + (12u << 20));    // 4 MB  [2048][1024] (RoPE'd, x log2e/8)
  u16* Kb  = (u16*)(ws + (16u << 20));    // 4 MB
  u16* Vb  = (u16*)(ws + (20u << 20));    // 4 MB
  u16* Vt  = (u16*)(ws + (24u << 20));    // 4 MB  [16][64][2048]
  u16* Ab  = (u16*)(ws + (28u << 20));    // 4 MB  attn out bf16
  float* Mpart = (float*)(ws + (32u << 20));  // 1 MB  [16*64*8][32]
  float* Lpart = (float*)(ws + (33u << 20));  // 1 MB
  u16*   Opart = (u16*)(ws + (34u << 20));    // 32 MB [16*64*8][2048]

  convert_x<<<2048, 256, 0, stream>>>(X, Xb);
  transpose_w<<<dim3(16, 16, 4), 256, 0, stream>>>(wq, wk, wv, wo, Wtq, Wtk, Wtv, Wto);
  gemm_bf16<64, 128, 3, false><<<dim3(24, 32), 256, 0, stream>>>(Xb, Wtq, Wtk, Wtv, Qb, Kb, Vb, nullptr);
  rope_qk<<<4096, 256, 0, stream>>>(Qb, Kb, pos);
  v_transpose<<<dim3(32, 16), 256, 0, stream>>>(Vb, Vt);
  attn_partial<<<1152, 256, 0, stream>>>(Qb, Kb, Vt, amask, Mpart, Lpart, Opart);
  attn_combine<<<dim3(64, 16), 256, 0, stream>>>(Mpart, Lpart, Opart, Ab);
  gemm_bf16<64, 64, 1, true><<<dim3(16, 32), 256, 0, stream>>>(Ab, Wto, nullptr, nullptr,
                                                               nullptr, nullptr, nullptr, out);
}